// Round 1
// baseline (1755.307 us; speedup 1.0000x reference)
//
#include <hip/hip_runtime.h>
#include <hip/hip_bf16.h>

#define IN_DIM 256
#define HDIM 128
#define CDIM 32

// ---------------- degree / normalization ----------------

__global__ void deg_init_kernel(float* __restrict__ deg, int n) {
    int i = blockIdx.x * blockDim.x + threadIdx.x;
    if (i < n) deg[i] = 1.0f;  // self-loop
}

__global__ void deg_count_kernel(const int* __restrict__ dst, float* __restrict__ deg, int e) {
    int i = blockIdx.x * blockDim.x + threadIdx.x;
    if (i < e) unsafeAtomicAdd(&deg[dst[i]], 1.0f);
}

__global__ void deg_finish_kernel(float* __restrict__ deg, int n) {
    int i = blockIdx.x * blockDim.x + threadIdx.x;
    if (i < n) deg[i] = rsqrtf(deg[i]);  // deg >= 1 always (self-loop)
}

// ---------------- GEMM: C = A(MxK) @ W(KxNc) [+bias][relu] ----------------

template<int BM, int BN, int BK, int TM, int TN, bool BIAS, bool RELU>
__global__ __launch_bounds__(256) void gemm_kernel(
        const float* __restrict__ A, const float* __restrict__ W,
        const float* __restrict__ bias, float* __restrict__ C,
        int M, int K, int Nc) {
    __shared__ float As[BK][BM + 1];
    __shared__ float Bs[BK][BN + 1];
    const int t = threadIdx.x;
    const int tcols = BN / TN;               // threads along N
    const int tcol = t % tcols;
    const int trow = t / tcols;              // 0 .. BM/TM-1
    const int rowBase = blockIdx.x * BM;
    const int colBase = blockIdx.y * BN;

    float acc[TM][TN];
#pragma unroll
    for (int i = 0; i < TM; ++i)
#pragma unroll
        for (int j = 0; j < TN; ++j) acc[i][j] = 0.f;

    for (int k0 = 0; k0 < K; k0 += BK) {
        // A tile (BM x BK) stored transposed
        for (int i = t; i < BM * BK; i += 256) {
            int m = i / BK, kk = i % BK;
            int gr = rowBase + m;
            As[kk][m] = (gr < M) ? A[(size_t)gr * K + (k0 + kk)] : 0.f;
        }
        // W tile (BK x BN)
        for (int i = t; i < BK * BN; i += 256) {
            int kk = i / BN, nn = i % BN;
            Bs[kk][nn] = W[(size_t)(k0 + kk) * Nc + (colBase + nn)];
        }
        __syncthreads();
#pragma unroll
        for (int kk = 0; kk < BK; ++kk) {
            float a[TM], b[TN];
#pragma unroll
            for (int i = 0; i < TM; ++i) a[i] = As[kk][trow * TM + i];
#pragma unroll
            for (int j = 0; j < TN; ++j) b[j] = Bs[kk][tcol * TN + j];
#pragma unroll
            for (int i = 0; i < TM; ++i)
#pragma unroll
                for (int j = 0; j < TN; ++j) acc[i][j] += a[i] * b[j];
        }
        __syncthreads();
    }

#pragma unroll
    for (int i = 0; i < TM; ++i) {
        int gr = rowBase + trow * TM + i;
        if (gr >= M) continue;
#pragma unroll
        for (int j = 0; j < TN; ++j) {
            int gc = colBase + tcol * TN + j;
            float v = acc[i][j];
            if (BIAS) v += bias[gc];
            if (RELU) v = fmaxf(v, 0.f);
            C[(size_t)gr * Nc + gc] = v;
        }
    }
}

// ---------------- aggregation ----------------

// agg[i, :] = dinv[i]^2 * x[i, :]   (self-loop contribution; also zero-inits agg)
__global__ void selfloop_kernel(const float* __restrict__ x, const float* __restrict__ dinv,
                                float* __restrict__ agg, int n) {
    int i = blockIdx.x * blockDim.x + threadIdx.x;
    int total = n * HDIM;
    if (i >= total) return;
    int node = i >> 7;  // HDIM == 128
    float dv = dinv[node];
    agg[i] = dv * dv * x[i];
}

// one wavefront per edge: agg[dst, :] += dinv[src]*dinv[dst] * x[src, :]
__global__ void scatter_kernel(const float* __restrict__ x, const int* __restrict__ src,
                               const int* __restrict__ dst, const float* __restrict__ dinv,
                               float* __restrict__ agg, int e) {
    int w = (blockIdx.x * blockDim.x + threadIdx.x) >> 6;
    int lane = threadIdx.x & 63;
    if (w >= e) return;
    int s = src[w], d = dst[w];
    float norm = dinv[s] * dinv[d];
    const float* xs = x + (size_t)s * HDIM;
    float* ad = agg + (size_t)d * HDIM;
#pragma unroll
    for (int c = 0; c < HDIM; c += 64) {
        unsafeAtomicAdd(&ad[c + lane], norm * xs[c + lane]);
    }
}

__global__ void bias_relu_kernel(float* __restrict__ a, const float* __restrict__ b, int n) {
    int i = blockIdx.x * blockDim.x + threadIdx.x;
    int total = n * HDIM;
    if (i >= total) return;
    a[i] = fmaxf(a[i] + b[i & (HDIM - 1)], 0.f);
}

// ---------------- launch ----------------

extern "C" void kernel_launch(void* const* d_in, const int* in_sizes, int n_in,
                              void* d_out, int out_size, void* d_ws, size_t ws_size,
                              hipStream_t stream) {
    const float* X  = (const float*)d_in[0];
    const int*   ei = (const int*)d_in[1];
    const float* W1 = (const float*)d_in[2];
    const float* b1 = (const float*)d_in[3];
    const float* W2 = (const float*)d_in[4];
    const float* b2 = (const float*)d_in[5];
    const float* Wc = (const float*)d_in[6];
    const float* bc = (const float*)d_in[7];
    float* out = (float*)d_out;

    const int n = in_sizes[0] / IN_DIM;   // 100000
    const int e = in_sizes[1] / 2;        // 1600000
    const int* src = ei;
    const int* dst = ei + e;

    char* ws = (char*)d_ws;
    float* dinv = (float*)ws;
    size_t off = ((size_t)n * 4 + 255) & ~(size_t)255;
    size_t fsz = ((size_t)n * HDIM * 4 + 255) & ~(size_t)255;
    float* bufA = (float*)(ws + off);
    float* bufB = (float*)(ws + off + fsz);

    const int nb_n   = (n + 255) / 256;
    const int nb_e   = (e + 255) / 256;
    const int nb_nh  = (n * HDIM + 255) / 256;
    const int nb_ew  = (e + 3) / 4;          // 4 waves per 256-thread block

    // degrees -> dinv
    deg_init_kernel<<<nb_n, 256, 0, stream>>>(dinv, n);
    deg_count_kernel<<<nb_e, 256, 0, stream>>>(dst, dinv, e);
    deg_finish_kernel<<<nb_n, 256, 0, stream>>>(dinv, n);

    dim3 g64((n + 63) / 64, HDIM / 64);

    // layer 1: x1 = X @ W1 ; agg = sym-norm aggregate ; h1 = relu(agg + b1)
    gemm_kernel<64, 64, 16, 4, 4, false, false><<<g64, 256, 0, stream>>>(X, W1, nullptr, bufA, n, IN_DIM, HDIM);
    selfloop_kernel<<<nb_nh, 256, 0, stream>>>(bufA, dinv, bufB, n);
    scatter_kernel<<<nb_ew, 256, 0, stream>>>(bufA, src, dst, dinv, bufB, e);
    bias_relu_kernel<<<nb_nh, 256, 0, stream>>>(bufB, b1, n);

    // layer 2
    gemm_kernel<64, 64, 16, 4, 4, false, false><<<g64, 256, 0, stream>>>(bufB, W2, nullptr, bufA, n, HDIM, HDIM);
    selfloop_kernel<<<nb_nh, 256, 0, stream>>>(bufA, dinv, bufB, n);
    scatter_kernel<<<nb_ew, 256, 0, stream>>>(bufA, src, dst, dinv, bufB, e);
    bias_relu_kernel<<<nb_nh, 256, 0, stream>>>(bufB, b2, n);

    // classifier: out = h2 @ Wc + bc
    dim3 gc((n + 63) / 64, CDIM / 32);
    gemm_kernel<64, 32, 16, 4, 2, true, false><<<gc, 256, 0, stream>>>(bufB, Wc, bc, out, n, HDIM, CDIM);
}

// Round 2
// 770.272 us; speedup vs baseline: 2.2788x; 2.2788x over previous
//
#include <hip/hip_runtime.h>
#include <hip/hip_bf16.h>

#define IN_DIM 256
#define HDIM 128
#define CDIM 32

// ---------------- CSR build ----------------

__global__ void zero_kernel(int* __restrict__ p, int n) {
    int i = blockIdx.x * blockDim.x + threadIdx.x;
    if (i < n) p[i] = 0;
}

__global__ void degi_kernel(const int* __restrict__ dst, int* __restrict__ deg, int e) {
    int i = blockIdx.x * blockDim.x + threadIdx.x;
    if (i < e) atomicAdd(&deg[dst[i]], 1);
}

__global__ void dinv_kernel(const int* __restrict__ deg, float* __restrict__ dinv, int n) {
    int i = blockIdx.x * blockDim.x + threadIdx.x;
    if (i < n) dinv[i] = rsqrtf((float)(deg[i] + 1));  // +1 self-loop
}

// block scans 1024 elements (256 threads x 4)
__global__ __launch_bounds__(256) void scan1_kernel(const int* __restrict__ deg,
                                                    int* __restrict__ part,
                                                    int* __restrict__ btot, int n) {
    __shared__ int sd[256];
    int t = threadIdx.x;
    int base = blockIdx.x * 1024 + t * 4;
    int v[4], sum = 0;
#pragma unroll
    for (int j = 0; j < 4; ++j) { int idx = base + j; v[j] = (idx < n) ? deg[idx] : 0; sum += v[j]; }
    sd[t] = sum;
    __syncthreads();
    for (int off = 1; off < 256; off <<= 1) {
        int x = (t >= off) ? sd[t - off] : 0;
        __syncthreads();
        sd[t] += x;
        __syncthreads();
    }
    int excl = sd[t] - sum;
#pragma unroll
    for (int j = 0; j < 4; ++j) { int idx = base + j; if (idx < n) part[idx] = excl; excl += v[j]; }
    if (t == 255) btot[blockIdx.x] = sd[255];
}

// scan up to 256 block totals (single block)
__global__ __launch_bounds__(256) void scan2_kernel(const int* __restrict__ btot,
                                                    int* __restrict__ boff, int nb) {
    __shared__ int sd[256];
    int t = threadIdx.x;
    int v = (t < nb) ? btot[t] : 0;
    sd[t] = v;
    __syncthreads();
    for (int off = 1; off < 256; off <<= 1) {
        int x = (t >= off) ? sd[t - off] : 0;
        __syncthreads();
        sd[t] += x;
        __syncthreads();
    }
    if (t < nb) boff[t] = sd[t] - v;
}

__global__ void scan3_kernel(const int* __restrict__ part, const int* __restrict__ boff,
                             int* __restrict__ row_ptr, int* __restrict__ cursor,
                             int n, int e) {
    int i = blockIdx.x * blockDim.x + threadIdx.x;
    if (i < n) {
        int v = part[i] + boff[i >> 10];
        row_ptr[i] = v;
        cursor[i] = v;
    } else if (i == n) {
        row_ptr[n] = e;
    }
}

__global__ void place_kernel(const int* __restrict__ src, const int* __restrict__ dst,
                             int* __restrict__ cursor, int* __restrict__ csr_src, int e) {
    int i = blockIdx.x * blockDim.x + threadIdx.x;
    if (i < e) {
        int pos = atomicAdd(&cursor[dst[i]], 1);
        csr_src[pos] = src[i];
    }
}

// ---------------- GEMM: C = A(MxK) @ W(KxNc) [+bias] ----------------

template<int BM, int BN, int BK, int TM, int TN, bool BIAS>
__global__ __launch_bounds__(256) void gemm_kernel(
        const float* __restrict__ A, const float* __restrict__ W,
        const float* __restrict__ bias, float* __restrict__ C,
        int M, int K, int Nc) {
    __shared__ float As[BK][BM + 1];
    __shared__ float Bs[BK][BN + 1];
    const int t = threadIdx.x;
    const int tcols = BN / TN;
    const int tcol = t % tcols;
    const int trow = t / tcols;
    const int rowBase = blockIdx.x * BM;
    const int colBase = blockIdx.y * BN;

    float acc[TM][TN];
#pragma unroll
    for (int i = 0; i < TM; ++i)
#pragma unroll
        for (int j = 0; j < TN; ++j) acc[i][j] = 0.f;

    for (int k0 = 0; k0 < K; k0 += BK) {
        for (int i = t; i < BM * BK; i += 256) {
            int m = i / BK, kk = i % BK;
            int gr = rowBase + m;
            As[kk][m] = (gr < M) ? A[(size_t)gr * K + (k0 + kk)] : 0.f;
        }
        for (int i = t; i < BK * BN; i += 256) {
            int kk = i / BN, nn = i % BN;
            Bs[kk][nn] = W[(size_t)(k0 + kk) * Nc + (colBase + nn)];
        }
        __syncthreads();
#pragma unroll
        for (int kk = 0; kk < BK; ++kk) {
            float a[TM], b[TN];
#pragma unroll
            for (int i = 0; i < TM; ++i) a[i] = As[kk][trow * TM + i];
#pragma unroll
            for (int j = 0; j < TN; ++j) b[j] = Bs[kk][tcol * TN + j];
#pragma unroll
            for (int i = 0; i < TM; ++i)
#pragma unroll
                for (int j = 0; j < TN; ++j) acc[i][j] += a[i] * b[j];
        }
        __syncthreads();
    }

#pragma unroll
    for (int i = 0; i < TM; ++i) {
        int gr = rowBase + trow * TM + i;
        if (gr >= M) continue;
#pragma unroll
        for (int j = 0; j < TN; ++j) {
            int gc = colBase + tcol * TN + j;
            float v = acc[i][j];
            if (BIAS) v += bias[gc];
            C[(size_t)gr * Nc + gc] = v;
        }
    }
}

// ---------------- gather aggregation (fused self-loop + bias + relu) ----------------
// out[d,:] = relu( dinv[d] * ( sum_{s in N(d)} dinv[s]*x[s,:] + dinv[d]*x[d,:] ) + bias )

__global__ __launch_bounds__(256) void gather_kernel(
        const float* __restrict__ x, const int* __restrict__ row_ptr,
        const int* __restrict__ csr_src, const float* __restrict__ dinv,
        const float* __restrict__ bias, float* __restrict__ out, int n) {
    int node = blockIdx.x * 4 + (threadIdx.x >> 6);
    if (node >= n) return;
    int lane = threadIdx.x & 63;
    const float2* xv = (const float2*)x;
    float dd = dinv[node];
    float2 self = xv[(size_t)node * 64 + lane];
    float accx = dd * self.x, accy = dd * self.y;
    int p = row_ptr[node], end = row_ptr[node + 1];
    for (; p + 1 < end; p += 2) {
        int s0 = csr_src[p], s1 = csr_src[p + 1];
        float w0 = dinv[s0], w1 = dinv[s1];
        float2 v0 = xv[(size_t)s0 * 64 + lane];
        float2 v1 = xv[(size_t)s1 * 64 + lane];
        accx += w0 * v0.x + w1 * v1.x;
        accy += w0 * v0.y + w1 * v1.y;
    }
    if (p < end) {
        int s0 = csr_src[p];
        float w0 = dinv[s0];
        float2 v0 = xv[(size_t)s0 * 64 + lane];
        accx += w0 * v0.x;
        accy += w0 * v0.y;
    }
    float2 bb = ((const float2*)bias)[lane];
    float2 r;
    r.x = fmaxf(accx * dd + bb.x, 0.f);
    r.y = fmaxf(accy * dd + bb.y, 0.f);
    ((float2*)out)[(size_t)node * 64 + lane] = r;
}

// ---------------- launch ----------------

extern "C" void kernel_launch(void* const* d_in, const int* in_sizes, int n_in,
                              void* d_out, int out_size, void* d_ws, size_t ws_size,
                              hipStream_t stream) {
    const float* X  = (const float*)d_in[0];
    const int*   ei = (const int*)d_in[1];
    const float* W1 = (const float*)d_in[2];
    const float* b1 = (const float*)d_in[3];
    const float* W2 = (const float*)d_in[4];
    const float* b2 = (const float*)d_in[5];
    const float* Wc = (const float*)d_in[6];
    const float* bc = (const float*)d_in[7];
    float* out = (float*)d_out;

    const int n = in_sizes[0] / IN_DIM;   // 100000
    const int e = in_sizes[1] / 2;        // 1600000
    const int* src = ei;
    const int* dst = ei + e;

    // workspace layout
    char* ws = (char*)d_ws;
    auto align = [](size_t x) { return (x + 255) & ~(size_t)255; };
    size_t off = 0;
    float* dinv   = (float*)(ws + off); off += align((size_t)n * 4);
    int* deg      = (int*)(ws + off);   off += align((size_t)n * 4);
    int* part     = (int*)(ws + off);   off += align((size_t)n * 4);
    int* cursor   = (int*)(ws + off);   off += align((size_t)n * 4);
    int* row_ptr  = (int*)(ws + off);   off += align((size_t)(n + 1) * 4);
    int* btot     = (int*)(ws + off);   off += align(256 * 4);
    int* boff     = (int*)(ws + off);   off += align(256 * 4);
    int* csr_src  = (int*)(ws + off);   off += align((size_t)e * 4);
    float* bufA   = (float*)(ws + off); off += align((size_t)n * HDIM * 4);
    float* bufB   = (float*)(ws + off); off += align((size_t)n * HDIM * 4);

    const int nb_n  = (n + 255) / 256;
    const int nb_n1 = (n + 256) / 256;   // covers n+1 ids
    const int nb_e  = (e + 255) / 256;
    const int nb1024 = (n + 1023) / 1024;

    // ---- CSR build (shared by both layers) ----
    zero_kernel<<<nb_n, 256, 0, stream>>>(deg, n);
    degi_kernel<<<nb_e, 256, 0, stream>>>(dst, deg, e);
    dinv_kernel<<<nb_n, 256, 0, stream>>>(deg, dinv, n);
    scan1_kernel<<<nb1024, 256, 0, stream>>>(deg, part, btot, n);
    scan2_kernel<<<1, 256, 0, stream>>>(btot, boff, nb1024);
    scan3_kernel<<<nb_n1, 256, 0, stream>>>(part, boff, row_ptr, cursor, n, e);
    place_kernel<<<nb_e, 256, 0, stream>>>(src, dst, cursor, csr_src, e);

    dim3 g64((n + 63) / 64, HDIM / 64);
    const int nb_g = (n + 3) / 4;  // 4 nodes (waves) per block

    // layer 1
    gemm_kernel<64, 64, 16, 4, 4, false><<<g64, 256, 0, stream>>>(X, W1, nullptr, bufA, n, IN_DIM, HDIM);
    gather_kernel<<<nb_g, 256, 0, stream>>>(bufA, row_ptr, csr_src, dinv, b1, bufB, n);

    // layer 2
    gemm_kernel<64, 64, 16, 4, 4, false><<<g64, 256, 0, stream>>>(bufB, W2, nullptr, bufA, n, HDIM, HDIM);
    gather_kernel<<<nb_g, 256, 0, stream>>>(bufA, row_ptr, csr_src, dinv, b2, bufB, n);

    // classifier
    dim3 gc((n + 63) / 64, CDIM / 32);
    gemm_kernel<64, 32, 16, 4, 2, true><<<gc, 256, 0, stream>>>(bufB, Wc, bc, out, n, HDIM, CDIM);
}

// Round 3
// 616.455 us; speedup vs baseline: 2.8474x; 1.2495x over previous
//
#include <hip/hip_runtime.h>
#include <hip/hip_bf16.h>

#define IN_DIM 256
#define HDIM 128
#define CDIM 32

typedef __attribute__((ext_vector_type(8))) short bf16x8;
typedef __attribute__((ext_vector_type(4))) float f32x4;

__device__ __forceinline__ short f2bf(float x) {
    unsigned u = __float_as_uint(x);
    unsigned r = (u + 0x7FFFu + ((u >> 16) & 1u)) >> 16;  // RN-even
    return (short)r;
}
__device__ __forceinline__ float bf2f(short s) {
    return __uint_as_float(((unsigned)(unsigned short)s) << 16);
}
__device__ __forceinline__ int swz4(int r) { return (r & 3) ^ ((r >> 2) & 3); }

// ---------------- CSR build ----------------

__global__ void zero_kernel(int* __restrict__ p, int n) {
    int i = blockIdx.x * blockDim.x + threadIdx.x;
    if (i < n) p[i] = 0;
}

__global__ void degi_kernel(const int* __restrict__ dst, int* __restrict__ deg, int e) {
    int i = blockIdx.x * blockDim.x + threadIdx.x;
    if (i < e) atomicAdd(&deg[dst[i]], 1);
}

__global__ void dinv_kernel(const int* __restrict__ deg, float* __restrict__ dinv, int n) {
    int i = blockIdx.x * blockDim.x + threadIdx.x;
    if (i < n) dinv[i] = rsqrtf((float)(deg[i] + 1));  // +1 self-loop
}

__global__ __launch_bounds__(256) void scan1_kernel(const int* __restrict__ deg,
                                                    int* __restrict__ part,
                                                    int* __restrict__ btot, int n) {
    __shared__ int sd[256];
    int t = threadIdx.x;
    int base = blockIdx.x * 1024 + t * 4;
    int v[4], sum = 0;
#pragma unroll
    for (int j = 0; j < 4; ++j) { int idx = base + j; v[j] = (idx < n) ? deg[idx] : 0; sum += v[j]; }
    sd[t] = sum;
    __syncthreads();
    for (int off = 1; off < 256; off <<= 1) {
        int x = (t >= off) ? sd[t - off] : 0;
        __syncthreads();
        sd[t] += x;
        __syncthreads();
    }
    int excl = sd[t] - sum;
#pragma unroll
    for (int j = 0; j < 4; ++j) { int idx = base + j; if (idx < n) part[idx] = excl; excl += v[j]; }
    if (t == 255) btot[blockIdx.x] = sd[255];
}

__global__ __launch_bounds__(256) void scan2_kernel(const int* __restrict__ btot,
                                                    int* __restrict__ boff, int nb) {
    __shared__ int sd[256];
    int t = threadIdx.x;
    int v = (t < nb) ? btot[t] : 0;
    sd[t] = v;
    __syncthreads();
    for (int off = 1; off < 256; off <<= 1) {
        int x = (t >= off) ? sd[t - off] : 0;
        __syncthreads();
        sd[t] += x;
        __syncthreads();
    }
    if (t < nb) boff[t] = sd[t] - v;
}

__global__ void scan3_kernel(const int* __restrict__ part, const int* __restrict__ boff,
                             int* __restrict__ row_ptr, int* __restrict__ cursor,
                             int n, int e) {
    int i = blockIdx.x * blockDim.x + threadIdx.x;
    if (i < n) {
        int v = part[i] + boff[i >> 10];
        row_ptr[i] = v;
        cursor[i] = v;
    } else if (i == n) {
        row_ptr[n] = e;
    }
}

__global__ void place_kernel(const int* __restrict__ src, const int* __restrict__ dst,
                             int* __restrict__ cursor, int* __restrict__ csr_src, int e) {
    int i = blockIdx.x * blockDim.x + threadIdx.x;
    if (i < e) {
        int pos = atomicAdd(&cursor[dst[i]], 1);
        csr_src[pos] = src[i];
    }
}

// ---------------- weight split fp32 -> (hi, lo) bf16 ----------------

__global__ void wsplit_kernel(const float* __restrict__ W, short* __restrict__ hi,
                              short* __restrict__ lo, int total) {
    int i = blockIdx.x * blockDim.x + threadIdx.x;
    if (i < total) {
        float x = W[i];
        short h = f2bf(x);
        hi[i] = h;
        lo[i] = f2bf(x - bf2f(h));
    }
}

// ---------------- MFMA GEMM: C = A(MxK fp32) @ W(KxBN, pre-split bf16) ----------------
// 3-pass split: Ahi@Whi + Alo@Whi + Ahi@Wlo. 128xBN block tile, BK=32 chunks.

template<int BN, int WR, int WC>
__global__ __launch_bounds__(256) void mfma_gemm_kernel(
        const float* __restrict__ A, const short* __restrict__ Whi,
        const short* __restrict__ Wlo, float* __restrict__ C, int M, int K) {
    constexpr int FM = 128 / WR / 16;
    constexpr int FN = BN / WC / 16;
    __shared__ __align__(16) short Ah[128 * 32];
    __shared__ __align__(16) short Al[128 * 32];
    __shared__ __align__(16) short Bh[BN * 32];
    __shared__ __align__(16) short Bl[BN * 32];

    const int t = threadIdx.x;
    const int rowBase = blockIdx.x * 128;
    const int l = t & 63, w = t >> 6;
    const int wr = w / WC, wc = w % WC;
    const int lrow = l & 15, g = l >> 4;

    f32x4 acc[FM][FN];
#pragma unroll
    for (int i = 0; i < FM; ++i)
#pragma unroll
        for (int j = 0; j < FN; ++j) acc[i][j] = f32x4{0.f, 0.f, 0.f, 0.f};

    for (int k0 = 0; k0 < K; k0 += 32) {
        // ---- stage A chunk (128 x 32 fp32 -> hi/lo bf16, swizzled) ----
#pragma unroll
        for (int i = 0; i < 4; ++i) {
            int f = t + 256 * i;            // float4 index 0..1023
            int r = f >> 3, c4 = f & 7;     // row, float4-col
            int gr = rowBase + r;
            float4 v = make_float4(0.f, 0.f, 0.f, 0.f);
            if (gr < M) v = ((const float4*)A)[(size_t)gr * (K >> 2) + (k0 >> 2) + c4];
            short h0 = f2bf(v.x), h1 = f2bf(v.y), h2 = f2bf(v.z), h3 = f2bf(v.w);
            short e0 = f2bf(v.x - bf2f(h0)), e1 = f2bf(v.y - bf2f(h1));
            short e2 = f2bf(v.z - bf2f(h2)), e3 = f2bf(v.w - bf2f(h3));
            int idx = r * 8 + (((c4 >> 1) ^ swz4(r)) << 1) + (c4 & 1);  // short4 units
            ((short4*)Ah)[idx] = make_short4(h0, h1, h2, h3);
            ((short4*)Al)[idx] = make_short4(e0, e1, e2, e3);
        }
        // ---- stage W chunk transposed: Bs[n][k] (BN x 32 bf16, swizzled) ----
#pragma unroll
        for (int u0 = 0; u0 < BN * 8; u0 += 256) {
            int u = u0 + t;
            int n = u % BN;
            int h = u / BN;                 // half-group 0..7 (4 k each)
            int kb = (k0 + h * 4) * BN + n;
            short w0 = Whi[kb], w1 = Whi[kb + BN], w2 = Whi[kb + 2 * BN], w3 = Whi[kb + 3 * BN];
            short y0 = Wlo[kb], y1 = Wlo[kb + BN], y2 = Wlo[kb + 2 * BN], y3 = Wlo[kb + 3 * BN];
            int idx = n * 8 + (((h >> 1) ^ swz4(n)) << 1) + (h & 1);
            ((short4*)Bh)[idx] = make_short4(w0, w1, w2, w3);
            ((short4*)Bl)[idx] = make_short4(y0, y1, y2, y3);
        }
        __syncthreads();

        bf16x8 ah[FM], al[FM], bh[FN], bl[FN];
#pragma unroll
        for (int fm = 0; fm < FM; ++fm) {
            int r = wr * (FM * 16) + fm * 16 + lrow;
            ah[fm] = ((const bf16x8*)Ah)[r * 4 + (g ^ swz4(r))];
        }
#pragma unroll
        for (int fn = 0; fn < FN; ++fn) {
            int n = wc * (FN * 16) + fn * 16 + lrow;
            bh[fn] = ((const bf16x8*)Bh)[n * 4 + (g ^ swz4(n))];
        }
#pragma unroll
        for (int fm = 0; fm < FM; ++fm)
#pragma unroll
            for (int fn = 0; fn < FN; ++fn)
                acc[fm][fn] = __builtin_amdgcn_mfma_f32_16x16x32_bf16(ah[fm], bh[fn], acc[fm][fn], 0, 0, 0);
#pragma unroll
        for (int fm = 0; fm < FM; ++fm) {
            int r = wr * (FM * 16) + fm * 16 + lrow;
            al[fm] = ((const bf16x8*)Al)[r * 4 + (g ^ swz4(r))];
        }
#pragma unroll
        for (int fm = 0; fm < FM; ++fm)
#pragma unroll
            for (int fn = 0; fn < FN; ++fn)
                acc[fm][fn] = __builtin_amdgcn_mfma_f32_16x16x32_bf16(al[fm], bh[fn], acc[fm][fn], 0, 0, 0);
#pragma unroll
        for (int fn = 0; fn < FN; ++fn) {
            int n = wc * (FN * 16) + fn * 16 + lrow;
            bl[fn] = ((const bf16x8*)Bl)[n * 4 + (g ^ swz4(n))];
        }
#pragma unroll
        for (int fm = 0; fm < FM; ++fm)
#pragma unroll
            for (int fn = 0; fn < FN; ++fn)
                acc[fm][fn] = __builtin_amdgcn_mfma_f32_16x16x32_bf16(ah[fm], bl[fn], acc[fm][fn], 0, 0, 0);
        __syncthreads();
    }

    // ---- store: C/D layout col=lane&15, row=(lane>>4)*4+reg ----
#pragma unroll
    for (int fm = 0; fm < FM; ++fm)
#pragma unroll
        for (int fn = 0; fn < FN; ++fn) {
            int col = wc * (FN * 16) + fn * 16 + lrow;
#pragma unroll
            for (int r = 0; r < 4; ++r) {
                int row = rowBase + wr * (FM * 16) + fm * 16 + g * 4 + r;
                if (row < M) C[(size_t)row * BN + col] = acc[fm][fn][r];
            }
        }
}

// ---------------- fp32 GEMM (classifier only) ----------------

template<int BM, int BN, int BK, int TM, int TN, bool BIAS>
__global__ __launch_bounds__(256) void gemm_kernel(
        const float* __restrict__ A, const float* __restrict__ W,
        const float* __restrict__ bias, float* __restrict__ C,
        int M, int K, int Nc) {
    __shared__ float As[BK][BM + 1];
    __shared__ float Bs[BK][BN + 1];
    const int t = threadIdx.x;
    const int tcols = BN / TN;
    const int tcol = t % tcols;
    const int trow = t / tcols;
    const int rowBase = blockIdx.x * BM;
    const int colBase = blockIdx.y * BN;

    float acc[TM][TN];
#pragma unroll
    for (int i = 0; i < TM; ++i)
#pragma unroll
        for (int j = 0; j < TN; ++j) acc[i][j] = 0.f;

    for (int k0 = 0; k0 < K; k0 += BK) {
        for (int i = t; i < BM * BK; i += 256) {
            int m = i / BK, kk = i % BK;
            int gr = rowBase + m;
            As[kk][m] = (gr < M) ? A[(size_t)gr * K + (k0 + kk)] : 0.f;
        }
        for (int i = t; i < BK * BN; i += 256) {
            int kk = i / BN, nn = i % BN;
            Bs[kk][nn] = W[(size_t)(k0 + kk) * Nc + (colBase + nn)];
        }
        __syncthreads();
#pragma unroll
        for (int kk = 0; kk < BK; ++kk) {
            float a[TM], b[TN];
#pragma unroll
            for (int i = 0; i < TM; ++i) a[i] = As[kk][trow * TM + i];
#pragma unroll
            for (int j = 0; j < TN; ++j) b[j] = Bs[kk][tcol * TN + j];
#pragma unroll
            for (int i = 0; i < TM; ++i)
#pragma unroll
                for (int j = 0; j < TN; ++j) acc[i][j] += a[i] * b[j];
        }
        __syncthreads();
    }

#pragma unroll
    for (int i = 0; i < TM; ++i) {
        int gr = rowBase + trow * TM + i;
        if (gr >= M) continue;
#pragma unroll
        for (int j = 0; j < TN; ++j) {
            int gc = colBase + tcol * TN + j;
            float v = acc[i][j];
            if (BIAS) v += bias[gc];
            C[(size_t)gr * Nc + gc] = v;
        }
    }
}

// ---------------- gather aggregation (fused self-loop + bias + relu) ----------------

__global__ __launch_bounds__(256) void gather_kernel(
        const float* __restrict__ x, const int* __restrict__ row_ptr,
        const int* __restrict__ csr_src, const float* __restrict__ dinv,
        const float* __restrict__ bias, float* __restrict__ out, int n) {
    int node = blockIdx.x * 4 + (threadIdx.x >> 6);
    if (node >= n) return;
    int lane = threadIdx.x & 63;
    const float2* xv = (const float2*)x;
    float dd = dinv[node];
    float2 self = xv[(size_t)node * 64 + lane];
    float accx = dd * self.x, accy = dd * self.y;
    int p = row_ptr[node], end = row_ptr[node + 1];
    for (; p + 1 < end; p += 2) {
        int s0 = csr_src[p], s1 = csr_src[p + 1];
        float w0 = dinv[s0], w1 = dinv[s1];
        float2 v0 = xv[(size_t)s0 * 64 + lane];
        float2 v1 = xv[(size_t)s1 * 64 + lane];
        accx += w0 * v0.x + w1 * v1.x;
        accy += w0 * v0.y + w1 * v1.y;
    }
    if (p < end) {
        int s0 = csr_src[p];
        float w0 = dinv[s0];
        float2 v0 = xv[(size_t)s0 * 64 + lane];
        accx += w0 * v0.x;
        accy += w0 * v0.y;
    }
    float2 bb = ((const float2*)bias)[lane];
    float2 r;
    r.x = fmaxf(accx * dd + bb.x, 0.f);
    r.y = fmaxf(accy * dd + bb.y, 0.f);
    ((float2*)out)[(size_t)node * 64 + lane] = r;
}

// ---------------- launch ----------------

extern "C" void kernel_launch(void* const* d_in, const int* in_sizes, int n_in,
                              void* d_out, int out_size, void* d_ws, size_t ws_size,
                              hipStream_t stream) {
    const float* X  = (const float*)d_in[0];
    const int*   ei = (const int*)d_in[1];
    const float* W1 = (const float*)d_in[2];
    const float* b1 = (const float*)d_in[3];
    const float* W2 = (const float*)d_in[4];
    const float* b2 = (const float*)d_in[5];
    const float* Wc = (const float*)d_in[6];
    const float* bc = (const float*)d_in[7];
    float* out = (float*)d_out;

    const int n = in_sizes[0] / IN_DIM;   // 100000
    const int e = in_sizes[1] / 2;        // 1600000
    const int* src = ei;
    const int* dst = ei + e;

    // workspace layout
    char* ws = (char*)d_ws;
    auto align = [](size_t x) { return (x + 255) & ~(size_t)255; };
    size_t off = 0;
    float* dinv   = (float*)(ws + off); off += align((size_t)n * 4);
    int* deg      = (int*)(ws + off);   off += align((size_t)n * 4);
    int* part     = (int*)(ws + off);   off += align((size_t)n * 4);
    int* cursor   = (int*)(ws + off);   off += align((size_t)n * 4);
    int* row_ptr  = (int*)(ws + off);   off += align((size_t)(n + 1) * 4);
    int* btot     = (int*)(ws + off);   off += align(256 * 4);
    int* boff     = (int*)(ws + off);   off += align(256 * 4);
    int* csr_src  = (int*)(ws + off);   off += align((size_t)e * 4);
    short* whi1   = (short*)(ws + off); off += align((size_t)IN_DIM * HDIM * 2);
    short* wlo1   = (short*)(ws + off); off += align((size_t)IN_DIM * HDIM * 2);
    short* whi2   = (short*)(ws + off); off += align((size_t)HDIM * HDIM * 2);
    short* wlo2   = (short*)(ws + off); off += align((size_t)HDIM * HDIM * 2);
    float* bufA   = (float*)(ws + off); off += align((size_t)n * HDIM * 4);
    float* bufB   = (float*)(ws + off); off += align((size_t)n * HDIM * 4);

    const int nb_n  = (n + 255) / 256;
    const int nb_n1 = (n + 256) / 256;
    const int nb_e  = (e + 255) / 256;
    const int nb1024 = (n + 1023) / 1024;

    // ---- weight split ----
    wsplit_kernel<<<(IN_DIM * HDIM + 255) / 256, 256, 0, stream>>>(W1, whi1, wlo1, IN_DIM * HDIM);
    wsplit_kernel<<<(HDIM * HDIM + 255) / 256, 256, 0, stream>>>(W2, whi2, wlo2, HDIM * HDIM);

    // ---- CSR build (shared by both layers) ----
    zero_kernel<<<nb_n, 256, 0, stream>>>(deg, n);
    degi_kernel<<<nb_e, 256, 0, stream>>>(dst, deg, e);
    dinv_kernel<<<nb_n, 256, 0, stream>>>(deg, dinv, n);
    scan1_kernel<<<nb1024, 256, 0, stream>>>(deg, part, btot, n);
    scan2_kernel<<<1, 256, 0, stream>>>(btot, boff, nb1024);
    scan3_kernel<<<nb_n1, 256, 0, stream>>>(part, boff, row_ptr, cursor, n, e);
    place_kernel<<<nb_e, 256, 0, stream>>>(src, dst, cursor, csr_src, e);

    const int gBlocks = (n + 127) / 128;
    const int nb_g = (n + 3) / 4;

    // layer 1
    mfma_gemm_kernel<128, 2, 2><<<gBlocks, 256, 0, stream>>>(X, whi1, wlo1, bufA, n, IN_DIM);
    gather_kernel<<<nb_g, 256, 0, stream>>>(bufA, row_ptr, csr_src, dinv, b1, bufB, n);

    // layer 2
    mfma_gemm_kernel<128, 2, 2><<<gBlocks, 256, 0, stream>>>(bufB, whi2, wlo2, bufA, n, HDIM);
    gather_kernel<<<nb_g, 256, 0, stream>>>(bufA, row_ptr, csr_src, dinv, b2, bufB, n);

    // classifier
    dim3 gc((n + 63) / 64, CDIM / 32);
    gemm_kernel<64, 32, 16, 4, 2, true><<<gc, 256, 0, stream>>>(bufB, Wc, bc, out, n, HDIM, CDIM);
}

// Round 4
// 438.515 us; speedup vs baseline: 4.0028x; 1.4058x over previous
//
#include <hip/hip_runtime.h>
#include <hip/hip_bf16.h>
#include <hip/hip_fp16.h>

#define IN_DIM 256
#define HDIM 128
#define CDIM 32

typedef __attribute__((ext_vector_type(8))) short bf16x8;
typedef __attribute__((ext_vector_type(4))) float f32x4;

__device__ __forceinline__ short f2bf(float x) {
    unsigned u = __float_as_uint(x);
    unsigned r = (u + 0x7FFFu + ((u >> 16) & 1u)) >> 16;  // RN-even
    return (short)r;
}
__device__ __forceinline__ float bf2f(short s) {
    return __uint_as_float(((unsigned)(unsigned short)s) << 16);
}
__device__ __forceinline__ int swz4(int r) { return (r & 3) ^ ((r >> 2) & 3); }

// ---------------- CSR build ----------------

__global__ void zero_kernel(int* __restrict__ p, int n) {
    int i = blockIdx.x * blockDim.x + threadIdx.x;
    if (i < n) p[i] = 0;
}

__global__ void degi_kernel(const int* __restrict__ dst, int* __restrict__ deg, int e) {
    int i = blockIdx.x * blockDim.x + threadIdx.x;
    if (i < e) atomicAdd(&deg[dst[i]], 1);
}

__global__ void dinv_kernel(const int* __restrict__ deg, float* __restrict__ dinv, int n) {
    int i = blockIdx.x * blockDim.x + threadIdx.x;
    if (i < n) dinv[i] = rsqrtf((float)(deg[i] + 1));  // +1 self-loop
}

__global__ __launch_bounds__(256) void scan1_kernel(const int* __restrict__ deg,
                                                    int* __restrict__ part,
                                                    int* __restrict__ btot, int n) {
    __shared__ int sd[256];
    int t = threadIdx.x;
    int base = blockIdx.x * 1024 + t * 4;
    int v[4], sum = 0;
#pragma unroll
    for (int j = 0; j < 4; ++j) { int idx = base + j; v[j] = (idx < n) ? deg[idx] : 0; sum += v[j]; }
    sd[t] = sum;
    __syncthreads();
    for (int off = 1; off < 256; off <<= 1) {
        int x = (t >= off) ? sd[t - off] : 0;
        __syncthreads();
        sd[t] += x;
        __syncthreads();
    }
    int excl = sd[t] - sum;
#pragma unroll
    for (int j = 0; j < 4; ++j) { int idx = base + j; if (idx < n) part[idx] = excl; excl += v[j]; }
    if (t == 255) btot[blockIdx.x] = sd[255];
}

__global__ __launch_bounds__(256) void scan2_kernel(const int* __restrict__ btot,
                                                    int* __restrict__ boff, int nb) {
    __shared__ int sd[256];
    int t = threadIdx.x;
    int v = (t < nb) ? btot[t] : 0;
    sd[t] = v;
    __syncthreads();
    for (int off = 1; off < 256; off <<= 1) {
        int x = (t >= off) ? sd[t - off] : 0;
        __syncthreads();
        sd[t] += x;
        __syncthreads();
    }
    if (t < nb) boff[t] = sd[t] - v;
}

__global__ void scan3_kernel(const int* __restrict__ part, const int* __restrict__ boff,
                             int* __restrict__ row_ptr, int* __restrict__ cursor,
                             int n, int e) {
    int i = blockIdx.x * blockDim.x + threadIdx.x;
    if (i < n) {
        int v = part[i] + boff[i >> 10];
        row_ptr[i] = v;
        cursor[i] = v;
    } else if (i == n) {
        row_ptr[n] = e;
    }
}

__global__ void place_kernel(const int* __restrict__ src, const int* __restrict__ dst,
                             int* __restrict__ cursor, int* __restrict__ csr_src, int e) {
    int i = blockIdx.x * blockDim.x + threadIdx.x;
    if (i < e) {
        int pos = atomicAdd(&cursor[dst[i]], 1);
        csr_src[pos] = src[i];
    }
}

// ---------------- weight split fp32 -> (hi, lo) bf16 ----------------

__global__ void wsplit_kernel(const float* __restrict__ W, short* __restrict__ hi,
                              short* __restrict__ lo, int total) {
    int i = blockIdx.x * blockDim.x + threadIdx.x;
    if (i < total) {
        float x = W[i];
        short h = f2bf(x);
        hi[i] = h;
        lo[i] = f2bf(x - bf2f(h));
    }
}

// ---------------- MFMA GEMM: C = A(MxK fp32) @ W(KxBN, pre-split bf16) ----------------
// 3-pass split: Ahi@Whi + Alo@Whi + Ahi@Wlo. 128xBN block tile, BK=32 chunks.

template<int BN, int WR, int WC, bool BIAS, bool OUTH>
__global__ __launch_bounds__(256) void mfma_gemm_kernel(
        const float* __restrict__ A, const short* __restrict__ Whi,
        const short* __restrict__ Wlo, const float* __restrict__ bias,
        void* __restrict__ C, int M, int K) {
    constexpr int FM = 128 / WR / 16;
    constexpr int FN = BN / WC / 16;
    __shared__ __align__(16) short Ah[128 * 32];
    __shared__ __align__(16) short Al[128 * 32];
    __shared__ __align__(16) short Bh[BN * 32];
    __shared__ __align__(16) short Bl[BN * 32];

    const int t = threadIdx.x;
    const int rowBase = blockIdx.x * 128;
    const int l = t & 63, w = t >> 6;
    const int wr = w / WC, wc = w % WC;
    const int lrow = l & 15, g = l >> 4;

    f32x4 acc[FM][FN];
#pragma unroll
    for (int i = 0; i < FM; ++i)
#pragma unroll
        for (int j = 0; j < FN; ++j) acc[i][j] = f32x4{0.f, 0.f, 0.f, 0.f};

    for (int k0 = 0; k0 < K; k0 += 32) {
        // ---- stage A chunk (128 x 32 fp32 -> hi/lo bf16, swizzled) ----
#pragma unroll
        for (int i = 0; i < 4; ++i) {
            int f = t + 256 * i;            // float4 index 0..1023
            int r = f >> 3, c4 = f & 7;     // row, float4-col
            int gr = rowBase + r;
            float4 v = make_float4(0.f, 0.f, 0.f, 0.f);
            if (gr < M) v = ((const float4*)A)[(size_t)gr * (K >> 2) + (k0 >> 2) + c4];
            short h0 = f2bf(v.x), h1 = f2bf(v.y), h2 = f2bf(v.z), h3 = f2bf(v.w);
            short e0 = f2bf(v.x - bf2f(h0)), e1 = f2bf(v.y - bf2f(h1));
            short e2 = f2bf(v.z - bf2f(h2)), e3 = f2bf(v.w - bf2f(h3));
            int idx = r * 8 + (((c4 >> 1) ^ swz4(r)) << 1) + (c4 & 1);  // short4 units
            ((short4*)Ah)[idx] = make_short4(h0, h1, h2, h3);
            ((short4*)Al)[idx] = make_short4(e0, e1, e2, e3);
        }
        // ---- stage W chunk transposed: Bs[n][k] (BN x 32 bf16, swizzled) ----
#pragma unroll
        for (int u0 = 0; u0 < BN * 8; u0 += 256) {
            int u = u0 + t;
            int n = u % BN;
            int h = u / BN;                 // half-group 0..7 (4 k each)
            int kb = (k0 + h * 4) * BN + n;
            short w0 = Whi[kb], w1 = Whi[kb + BN], w2 = Whi[kb + 2 * BN], w3 = Whi[kb + 3 * BN];
            short y0 = Wlo[kb], y1 = Wlo[kb + BN], y2 = Wlo[kb + 2 * BN], y3 = Wlo[kb + 3 * BN];
            int idx = n * 8 + (((h >> 1) ^ swz4(n)) << 1) + (h & 1);
            ((short4*)Bh)[idx] = make_short4(w0, w1, w2, w3);
            ((short4*)Bl)[idx] = make_short4(y0, y1, y2, y3);
        }
        __syncthreads();

        bf16x8 ah[FM], al[FM], bh[FN], bl[FN];
#pragma unroll
        for (int fm = 0; fm < FM; ++fm) {
            int r = wr * (FM * 16) + fm * 16 + lrow;
            ah[fm] = ((const bf16x8*)Ah)[r * 4 + (g ^ swz4(r))];
        }
#pragma unroll
        for (int fn = 0; fn < FN; ++fn) {
            int n = wc * (FN * 16) + fn * 16 + lrow;
            bh[fn] = ((const bf16x8*)Bh)[n * 4 + (g ^ swz4(n))];
        }
#pragma unroll
        for (int fm = 0; fm < FM; ++fm)
#pragma unroll
            for (int fn = 0; fn < FN; ++fn)
                acc[fm][fn] = __builtin_amdgcn_mfma_f32_16x16x32_bf16(ah[fm], bh[fn], acc[fm][fn], 0, 0, 0);
#pragma unroll
        for (int fm = 0; fm < FM; ++fm) {
            int r = wr * (FM * 16) + fm * 16 + lrow;
            al[fm] = ((const bf16x8*)Al)[r * 4 + (g ^ swz4(r))];
        }
#pragma unroll
        for (int fm = 0; fm < FM; ++fm)
#pragma unroll
            for (int fn = 0; fn < FN; ++fn)
                acc[fm][fn] = __builtin_amdgcn_mfma_f32_16x16x32_bf16(al[fm], bh[fn], acc[fm][fn], 0, 0, 0);
#pragma unroll
        for (int fn = 0; fn < FN; ++fn) {
            int n = wc * (FN * 16) + fn * 16 + lrow;
            bl[fn] = ((const bf16x8*)Bl)[n * 4 + (g ^ swz4(n))];
        }
#pragma unroll
        for (int fm = 0; fm < FM; ++fm)
#pragma unroll
            for (int fn = 0; fn < FN; ++fn)
                acc[fm][fn] = __builtin_amdgcn_mfma_f32_16x16x32_bf16(ah[fm], bl[fn], acc[fm][fn], 0, 0, 0);
        __syncthreads();
    }

    // ---- store: C/D layout col=lane&15, row=(lane>>4)*4+reg ----
#pragma unroll
    for (int fm = 0; fm < FM; ++fm)
#pragma unroll
        for (int fn = 0; fn < FN; ++fn) {
            int col = wc * (FN * 16) + fn * 16 + lrow;
#pragma unroll
            for (int r = 0; r < 4; ++r) {
                int row = rowBase + wr * (FM * 16) + fm * 16 + g * 4 + r;
                if (row < M) {
                    float v = acc[fm][fn][r];
                    if (BIAS) v += bias[col];
                    if (OUTH) ((__half*)C)[(size_t)row * BN + col] = __float2half_rn(v);
                    else      ((float*)C)[(size_t)row * BN + col] = v;
                }
            }
        }
}

// ---------------- gather aggregation (fp16 rows; fused self-loop + bias + relu) ----------------
// out[d,:] = relu( dinv[d] * ( sum_{s in N(d)} dinv[s]*x[s,:] + dinv[d]*x[d,:] ) + bias )

__global__ __launch_bounds__(256) void gather_kernel(
        const __half* __restrict__ x, const int* __restrict__ row_ptr,
        const int* __restrict__ csr_src, const float* __restrict__ dinv,
        const float* __restrict__ bias, float* __restrict__ out, int n) {
    int node = __builtin_amdgcn_readfirstlane(blockIdx.x * 4 + (threadIdx.x >> 6));
    if (node >= n) return;
    int lane = threadIdx.x & 63;
    const __half2* xv = (const __half2*)x;   // row = 64 half2
    float dd = dinv[node];
    float2 self = __half22float2(xv[(size_t)node * 64 + lane]);
    float accx = dd * self.x, accy = dd * self.y;
    int p = row_ptr[node], end = row_ptr[node + 1];
    for (; p + 3 < end; p += 4) {
        int s0 = csr_src[p], s1 = csr_src[p + 1], s2 = csr_src[p + 2], s3 = csr_src[p + 3];
        float w0 = dinv[s0], w1 = dinv[s1], w2 = dinv[s2], w3 = dinv[s3];
        float2 v0 = __half22float2(xv[(size_t)s0 * 64 + lane]);
        float2 v1 = __half22float2(xv[(size_t)s1 * 64 + lane]);
        float2 v2 = __half22float2(xv[(size_t)s2 * 64 + lane]);
        float2 v3 = __half22float2(xv[(size_t)s3 * 64 + lane]);
        accx += w0 * v0.x + w1 * v1.x + w2 * v2.x + w3 * v3.x;
        accy += w0 * v0.y + w1 * v1.y + w2 * v2.y + w3 * v3.y;
    }
    for (; p < end; ++p) {
        int s0 = csr_src[p];
        float w0 = dinv[s0];
        float2 v0 = __half22float2(xv[(size_t)s0 * 64 + lane]);
        accx += w0 * v0.x;
        accy += w0 * v0.y;
    }
    float2 bb = ((const float2*)bias)[lane];
    float2 r;
    r.x = fmaxf(accx * dd + bb.x, 0.f);
    r.y = fmaxf(accy * dd + bb.y, 0.f);
    ((float2*)out)[(size_t)node * 64 + lane] = r;
}

// ---------------- launch ----------------

extern "C" void kernel_launch(void* const* d_in, const int* in_sizes, int n_in,
                              void* d_out, int out_size, void* d_ws, size_t ws_size,
                              hipStream_t stream) {
    const float* X  = (const float*)d_in[0];
    const int*   ei = (const int*)d_in[1];
    const float* W1 = (const float*)d_in[2];
    const float* b1 = (const float*)d_in[3];
    const float* W2 = (const float*)d_in[4];
    const float* b2 = (const float*)d_in[5];
    const float* Wc = (const float*)d_in[6];
    const float* bc = (const float*)d_in[7];
    float* out = (float*)d_out;

    const int n = in_sizes[0] / IN_DIM;   // 100000
    const int e = in_sizes[1] / 2;        // 1600000
    const int* src = ei;
    const int* dst = ei + e;

    // workspace layout
    char* ws = (char*)d_ws;
    auto align = [](size_t x) { return (x + 255) & ~(size_t)255; };
    size_t off = 0;
    float* dinv   = (float*)(ws + off); off += align((size_t)n * 4);
    int* deg      = (int*)(ws + off);   off += align((size_t)n * 4);
    int* part     = (int*)(ws + off);   off += align((size_t)n * 4);
    int* cursor   = (int*)(ws + off);   off += align((size_t)n * 4);
    int* row_ptr  = (int*)(ws + off);   off += align((size_t)(n + 1) * 4);
    int* btot     = (int*)(ws + off);   off += align(256 * 4);
    int* boff     = (int*)(ws + off);   off += align(256 * 4);
    int* csr_src  = (int*)(ws + off);   off += align((size_t)e * 4);
    short* whi1   = (short*)(ws + off); off += align((size_t)IN_DIM * HDIM * 2);
    short* wlo1   = (short*)(ws + off); off += align((size_t)IN_DIM * HDIM * 2);
    short* whi2   = (short*)(ws + off); off += align((size_t)HDIM * HDIM * 2);
    short* wlo2   = (short*)(ws + off); off += align((size_t)HDIM * HDIM * 2);
    short* whic   = (short*)(ws + off); off += align((size_t)HDIM * CDIM * 2);
    short* wloc   = (short*)(ws + off); off += align((size_t)HDIM * CDIM * 2);
    __half* bufAh = (__half*)(ws + off); off += align((size_t)n * HDIM * 2);
    float* bufB   = (float*)(ws + off);  off += align((size_t)n * HDIM * 4);

    const int nb_n  = (n + 255) / 256;
    const int nb_n1 = (n + 256) / 256;
    const int nb_e  = (e + 255) / 256;
    const int nb1024 = (n + 1023) / 1024;

    // ---- weight split ----
    wsplit_kernel<<<(IN_DIM * HDIM + 255) / 256, 256, 0, stream>>>(W1, whi1, wlo1, IN_DIM * HDIM);
    wsplit_kernel<<<(HDIM * HDIM + 255) / 256, 256, 0, stream>>>(W2, whi2, wlo2, HDIM * HDIM);
    wsplit_kernel<<<(HDIM * CDIM + 255) / 256, 256, 0, stream>>>(Wc, whic, wloc, HDIM * CDIM);

    // ---- CSR build (shared by both layers) ----
    zero_kernel<<<nb_n, 256, 0, stream>>>(deg, n);
    degi_kernel<<<nb_e, 256, 0, stream>>>(dst, deg, e);
    dinv_kernel<<<nb_n, 256, 0, stream>>>(deg, dinv, n);
    scan1_kernel<<<nb1024, 256, 0, stream>>>(deg, part, btot, n);
    scan2_kernel<<<1, 256, 0, stream>>>(btot, boff, nb1024);
    scan3_kernel<<<nb_n1, 256, 0, stream>>>(part, boff, row_ptr, cursor, n, e);
    place_kernel<<<nb_e, 256, 0, stream>>>(src, dst, cursor, csr_src, e);

    const int gBlocks = (n + 127) / 128;
    const int nb_g = (n + 3) / 4;

    // layer 1
    mfma_gemm_kernel<128, 2, 2, false, true><<<gBlocks, 256, 0, stream>>>(X, whi1, wlo1, nullptr, bufAh, n, IN_DIM);
    gather_kernel<<<nb_g, 256, 0, stream>>>(bufAh, row_ptr, csr_src, dinv, b1, bufB, n);

    // layer 2
    mfma_gemm_kernel<128, 2, 2, false, true><<<gBlocks, 256, 0, stream>>>(bufB, whi2, wlo2, nullptr, bufAh, n, HDIM);
    gather_kernel<<<nb_g, 256, 0, stream>>>(bufAh, row_ptr, csr_src, dinv, b2, bufB, n);

    // classifier: out = h2 @ Wc + bc  (MFMA, fp32 out)
    mfma_gemm_kernel<32, 2, 2, true, false><<<gBlocks, 256, 0, stream>>>(bufB, whic, wloc, bc, out, n, HDIM);
}

// Round 5
// 402.921 us; speedup vs baseline: 4.3565x; 1.0883x over previous
//
#include <hip/hip_runtime.h>
#include <hip/hip_bf16.h>
#include <hip/hip_fp16.h>

#define IN_DIM 256
#define HDIM 128
#define CDIM 32

typedef __attribute__((ext_vector_type(8))) short bf16x8;
typedef __attribute__((ext_vector_type(4))) float f32x4;

__device__ __forceinline__ short f2bf(float x) {
    unsigned u = __float_as_uint(x);
    unsigned r = (u + 0x7FFFu + ((u >> 16) & 1u)) >> 16;  // RN-even
    return (short)r;
}
__device__ __forceinline__ float bf2f(short s) {
    return __uint_as_float(((unsigned)(unsigned short)s) << 16);
}
__device__ __forceinline__ int swz4(int r) { return (r & 3) ^ ((r >> 2) & 3); }

// ---------------- CSR build ----------------

__global__ void zero_kernel(int* __restrict__ p, int n) {
    int i = blockIdx.x * blockDim.x + threadIdx.x;
    if (i < n) p[i] = 0;
}

__global__ void degi_kernel(const int* __restrict__ dst, int* __restrict__ deg, int e) {
    int i = blockIdx.x * blockDim.x + threadIdx.x;
    if (i < e) atomicAdd(&deg[dst[i]], 1);
}

__global__ void dinv_kernel(const int* __restrict__ deg, float* __restrict__ dinv, int n) {
    int i = blockIdx.x * blockDim.x + threadIdx.x;
    if (i < n) dinv[i] = rsqrtf((float)(deg[i] + 1));  // +1 self-loop
}

__global__ __launch_bounds__(256) void scan1_kernel(const int* __restrict__ deg,
                                                    int* __restrict__ part,
                                                    int* __restrict__ btot, int n) {
    __shared__ int sd[256];
    int t = threadIdx.x;
    int base = blockIdx.x * 1024 + t * 4;
    int v[4], sum = 0;
#pragma unroll
    for (int j = 0; j < 4; ++j) { int idx = base + j; v[j] = (idx < n) ? deg[idx] : 0; sum += v[j]; }
    sd[t] = sum;
    __syncthreads();
    for (int off = 1; off < 256; off <<= 1) {
        int x = (t >= off) ? sd[t - off] : 0;
        __syncthreads();
        sd[t] += x;
        __syncthreads();
    }
    int excl = sd[t] - sum;
#pragma unroll
    for (int j = 0; j < 4; ++j) { int idx = base + j; if (idx < n) part[idx] = excl; excl += v[j]; }
    if (t == 255) btot[blockIdx.x] = sd[255];
}

__global__ __launch_bounds__(256) void scan2_kernel(const int* __restrict__ btot,
                                                    int* __restrict__ boff, int nb) {
    __shared__ int sd[256];
    int t = threadIdx.x;
    int v = (t < nb) ? btot[t] : 0;
    sd[t] = v;
    __syncthreads();
    for (int off = 1; off < 256; off <<= 1) {
        int x = (t >= off) ? sd[t - off] : 0;
        __syncthreads();
        sd[t] += x;
        __syncthreads();
    }
    if (t < nb) boff[t] = sd[t] - v;
}

__global__ void scan3_kernel(const int* __restrict__ part, const int* __restrict__ boff,
                             int* __restrict__ row_ptr, int* __restrict__ cursor,
                             int n, int e) {
    int i = blockIdx.x * blockDim.x + threadIdx.x;
    if (i < n) {
        int v = part[i] + boff[i >> 10];
        row_ptr[i] = v;
        cursor[i] = v;
    } else if (i == n) {
        row_ptr[n] = e;
    }
}

// range-partitioned edge placement: 8 dst-range passes inside one kernel.
// Ranges touch disjoint cursor/csr regions, so no inter-pass sync is needed;
// rough temporal alignment keeps the active csr span L2-resident.
__global__ __launch_bounds__(256) void place_mp_kernel(
        const int* __restrict__ src, const int* __restrict__ dst,
        int* __restrict__ cursor, int* __restrict__ csr_src,
        int e, int n, int rs) {
    const int stride = gridDim.x * blockDim.x;
    const int tid0 = blockIdx.x * blockDim.x + threadIdx.x;
    const int np = (n + rs - 1) / rs;
    for (int p = 0; p < np; ++p) {
        const int lo = p * rs, hi = lo + rs;
        for (int i = tid0; i < e; i += stride) {
            int d = dst[i];
            if (d >= lo && d < hi) {
                int pos = atomicAdd(&cursor[d], 1);
                csr_src[pos] = src[i];
            }
        }
    }
}

// ---------------- weight split fp32 -> (hi, lo) bf16 ----------------

__global__ void wsplit_kernel(const float* __restrict__ W, short* __restrict__ hi,
                              short* __restrict__ lo, int total) {
    int i = blockIdx.x * blockDim.x + threadIdx.x;
    if (i < total) {
        float x = W[i];
        short h = f2bf(x);
        hi[i] = h;
        lo[i] = f2bf(x - bf2f(h));
    }
}

// ---------------- MFMA GEMM: C = A(MxK fp32) @ W(KxBN, pre-split bf16) ----------------
// 3-pass split: Ahi@Whi + Alo@Whi + Ahi@Wlo. 128xBN block tile, BK=32 chunks.

template<int BN, int WR, int WC, bool BIAS, bool OUTH>
__global__ __launch_bounds__(256) void mfma_gemm_kernel(
        const float* __restrict__ A, const short* __restrict__ Whi,
        const short* __restrict__ Wlo, const float* __restrict__ bias,
        void* __restrict__ C, int M, int K) {
    constexpr int FM = 128 / WR / 16;
    constexpr int FN = BN / WC / 16;
    __shared__ __align__(16) short Ah[128 * 32];
    __shared__ __align__(16) short Al[128 * 32];
    __shared__ __align__(16) short Bh[BN * 32];
    __shared__ __align__(16) short Bl[BN * 32];

    const int t = threadIdx.x;
    const int rowBase = blockIdx.x * 128;
    const int l = t & 63, w = t >> 6;
    const int wr = w / WC, wc = w % WC;
    const int lrow = l & 15, g = l >> 4;

    f32x4 acc[FM][FN];
#pragma unroll
    for (int i = 0; i < FM; ++i)
#pragma unroll
        for (int j = 0; j < FN; ++j) acc[i][j] = f32x4{0.f, 0.f, 0.f, 0.f};

    for (int k0 = 0; k0 < K; k0 += 32) {
        // ---- stage A chunk (128 x 32 fp32 -> hi/lo bf16, swizzled) ----
#pragma unroll
        for (int i = 0; i < 4; ++i) {
            int f = t + 256 * i;            // float4 index 0..1023
            int r = f >> 3, c4 = f & 7;     // row, float4-col
            int gr = rowBase + r;
            float4 v = make_float4(0.f, 0.f, 0.f, 0.f);
            if (gr < M) v = ((const float4*)A)[(size_t)gr * (K >> 2) + (k0 >> 2) + c4];
            short h0 = f2bf(v.x), h1 = f2bf(v.y), h2 = f2bf(v.z), h3 = f2bf(v.w);
            short e0 = f2bf(v.x - bf2f(h0)), e1 = f2bf(v.y - bf2f(h1));
            short e2 = f2bf(v.z - bf2f(h2)), e3 = f2bf(v.w - bf2f(h3));
            int idx = r * 8 + (((c4 >> 1) ^ swz4(r)) << 1) + (c4 & 1);  // short4 units
            ((short4*)Ah)[idx] = make_short4(h0, h1, h2, h3);
            ((short4*)Al)[idx] = make_short4(e0, e1, e2, e3);
        }
        // ---- stage W chunk transposed: Bs[n][k] (BN x 32 bf16, swizzled) ----
#pragma unroll
        for (int u0 = 0; u0 < BN * 8; u0 += 256) {
            int u = u0 + t;
            int n = u % BN;
            int h = u / BN;                 // half-group 0..7 (4 k each)
            int kb = (k0 + h * 4) * BN + n;
            short w0 = Whi[kb], w1 = Whi[kb + BN], w2 = Whi[kb + 2 * BN], w3 = Whi[kb + 3 * BN];
            short y0 = Wlo[kb], y1 = Wlo[kb + BN], y2 = Wlo[kb + 2 * BN], y3 = Wlo[kb + 3 * BN];
            int idx = n * 8 + (((h >> 1) ^ swz4(n)) << 1) + (h & 1);
            ((short4*)Bh)[idx] = make_short4(w0, w1, w2, w3);
            ((short4*)Bl)[idx] = make_short4(y0, y1, y2, y3);
        }
        __syncthreads();

        bf16x8 ah[FM], al[FM], bh[FN], bl[FN];
#pragma unroll
        for (int fm = 0; fm < FM; ++fm) {
            int r = wr * (FM * 16) + fm * 16 + lrow;
            ah[fm] = ((const bf16x8*)Ah)[r * 4 + (g ^ swz4(r))];
        }
#pragma unroll
        for (int fn = 0; fn < FN; ++fn) {
            int n = wc * (FN * 16) + fn * 16 + lrow;
            bh[fn] = ((const bf16x8*)Bh)[n * 4 + (g ^ swz4(n))];
        }
#pragma unroll
        for (int fm = 0; fm < FM; ++fm)
#pragma unroll
            for (int fn = 0; fn < FN; ++fn)
                acc[fm][fn] = __builtin_amdgcn_mfma_f32_16x16x32_bf16(ah[fm], bh[fn], acc[fm][fn], 0, 0, 0);
#pragma unroll
        for (int fm = 0; fm < FM; ++fm) {
            int r = wr * (FM * 16) + fm * 16 + lrow;
            al[fm] = ((const bf16x8*)Al)[r * 4 + (g ^ swz4(r))];
        }
#pragma unroll
        for (int fm = 0; fm < FM; ++fm)
#pragma unroll
            for (int fn = 0; fn < FN; ++fn)
                acc[fm][fn] = __builtin_amdgcn_mfma_f32_16x16x32_bf16(al[fm], bh[fn], acc[fm][fn], 0, 0, 0);
#pragma unroll
        for (int fn = 0; fn < FN; ++fn) {
            int n = wc * (FN * 16) + fn * 16 + lrow;
            bl[fn] = ((const bf16x8*)Bl)[n * 4 + (g ^ swz4(n))];
        }
#pragma unroll
        for (int fm = 0; fm < FM; ++fm)
#pragma unroll
            for (int fn = 0; fn < FN; ++fn)
                acc[fm][fn] = __builtin_amdgcn_mfma_f32_16x16x32_bf16(ah[fm], bl[fn], acc[fm][fn], 0, 0, 0);
        __syncthreads();
    }

    // ---- store: C/D layout col=lane&15, row=(lane>>4)*4+reg ----
#pragma unroll
    for (int fm = 0; fm < FM; ++fm)
#pragma unroll
        for (int fn = 0; fn < FN; ++fn) {
            int col = wc * (FN * 16) + fn * 16 + lrow;
#pragma unroll
            for (int r = 0; r < 4; ++r) {
                int row = rowBase + wr * (FM * 16) + fm * 16 + g * 4 + r;
                if (row < M) {
                    float v = acc[fm][fn][r];
                    if (BIAS) v += bias[col];
                    if (OUTH) ((__half*)C)[(size_t)row * BN + col] = __float2half_rn(v);
                    else      ((float*)C)[(size_t)row * BN + col] = v;
                }
            }
        }
}

// ---------------- gather aggregation (fp16 rows; fused self-loop + bias + relu) ----------------
// out[d,:] = relu( dinv[d] * ( sum_{s in N(d)} dinv[s]*x[s,:] + dinv[d]*x[d,:] ) + bias )

__global__ __launch_bounds__(256) void gather_kernel(
        const __half* __restrict__ x, const int* __restrict__ row_ptr,
        const int* __restrict__ csr_src, const float* __restrict__ dinv,
        const float* __restrict__ bias, float* __restrict__ out, int n) {
    int node = __builtin_amdgcn_readfirstlane(blockIdx.x * 4 + (threadIdx.x >> 6));
    if (node >= n) return;
    int lane = threadIdx.x & 63;
    const __half2* xv = (const __half2*)x;   // row = 64 half2
    float dd = dinv[node];
    float2 self = __half22float2(xv[(size_t)node * 64 + lane]);
    float accx = dd * self.x, accy = dd * self.y;
    int p = row_ptr[node], end = row_ptr[node + 1];
    for (; p + 3 < end; p += 4) {
        int s0 = csr_src[p], s1 = csr_src[p + 1], s2 = csr_src[p + 2], s3 = csr_src[p + 3];
        float w0 = dinv[s0], w1 = dinv[s1], w2 = dinv[s2], w3 = dinv[s3];
        float2 v0 = __half22float2(xv[(size_t)s0 * 64 + lane]);
        float2 v1 = __half22float2(xv[(size_t)s1 * 64 + lane]);
        float2 v2 = __half22float2(xv[(size_t)s2 * 64 + lane]);
        float2 v3 = __half22float2(xv[(size_t)s3 * 64 + lane]);
        accx += w0 * v0.x + w1 * v1.x + w2 * v2.x + w3 * v3.x;
        accy += w0 * v0.y + w1 * v1.y + w2 * v2.y + w3 * v3.y;
    }
    for (; p < end; ++p) {
        int s0 = csr_src[p];
        float w0 = dinv[s0];
        float2 v0 = __half22float2(xv[(size_t)s0 * 64 + lane]);
        accx += w0 * v0.x;
        accy += w0 * v0.y;
    }
    float2 bb = ((const float2*)bias)[lane];
    float2 r;
    r.x = fmaxf(accx * dd + bb.x, 0.f);
    r.y = fmaxf(accy * dd + bb.y, 0.f);
    ((float2*)out)[(size_t)node * 64 + lane] = r;
}

// ---------------- launch ----------------

extern "C" void kernel_launch(void* const* d_in, const int* in_sizes, int n_in,
                              void* d_out, int out_size, void* d_ws, size_t ws_size,
                              hipStream_t stream) {
    const float* X  = (const float*)d_in[0];
    const int*   ei = (const int*)d_in[1];
    const float* W1 = (const float*)d_in[2];
    const float* b1 = (const float*)d_in[3];
    const float* W2 = (const float*)d_in[4];
    const float* b2 = (const float*)d_in[5];
    const float* Wc = (const float*)d_in[6];
    const float* bc = (const float*)d_in[7];
    float* out = (float*)d_out;

    const int n = in_sizes[0] / IN_DIM;   // 100000
    const int e = in_sizes[1] / 2;        // 1600000
    const int* src = ei;
    const int* dst = ei + e;

    // workspace layout
    char* ws = (char*)d_ws;
    auto align = [](size_t x) { return (x + 255) & ~(size_t)255; };
    size_t off = 0;
    float* dinv   = (float*)(ws + off); off += align((size_t)n * 4);
    int* deg      = (int*)(ws + off);   off += align((size_t)n * 4);
    int* part     = (int*)(ws + off);   off += align((size_t)n * 4);
    int* cursor   = (int*)(ws + off);   off += align((size_t)n * 4);
    int* row_ptr  = (int*)(ws + off);   off += align((size_t)(n + 1) * 4);
    int* btot     = (int*)(ws + off);   off += align(256 * 4);
    int* boff     = (int*)(ws + off);   off += align(256 * 4);
    int* csr_src  = (int*)(ws + off);   off += align((size_t)e * 4);
    short* whi1   = (short*)(ws + off); off += align((size_t)IN_DIM * HDIM * 2);
    short* wlo1   = (short*)(ws + off); off += align((size_t)IN_DIM * HDIM * 2);
    short* whi2   = (short*)(ws + off); off += align((size_t)HDIM * HDIM * 2);
    short* wlo2   = (short*)(ws + off); off += align((size_t)HDIM * HDIM * 2);
    short* whic   = (short*)(ws + off); off += align((size_t)HDIM * CDIM * 2);
    short* wloc   = (short*)(ws + off); off += align((size_t)HDIM * CDIM * 2);
    __half* bufAh = (__half*)(ws + off); off += align((size_t)n * HDIM * 2);
    float* bufB   = (float*)(ws + off);  off += align((size_t)n * HDIM * 4);

    const int nb_n  = (n + 255) / 256;
    const int nb_n1 = (n + 256) / 256;
    const int nb_e  = (e + 255) / 256;
    const int nb1024 = (n + 1023) / 1024;

    // ---- weight split ----
    wsplit_kernel<<<(IN_DIM * HDIM + 255) / 256, 256, 0, stream>>>(W1, whi1, wlo1, IN_DIM * HDIM);
    wsplit_kernel<<<(HDIM * HDIM + 255) / 256, 256, 0, stream>>>(W2, whi2, wlo2, HDIM * HDIM);
    wsplit_kernel<<<(HDIM * CDIM + 255) / 256, 256, 0, stream>>>(Wc, whic, wloc, HDIM * CDIM);

    // ---- CSR build (shared by both layers) ----
    zero_kernel<<<nb_n, 256, 0, stream>>>(deg, n);
    degi_kernel<<<nb_e, 256, 0, stream>>>(dst, deg, e);
    dinv_kernel<<<nb_n, 256, 0, stream>>>(deg, dinv, n);
    scan1_kernel<<<nb1024, 256, 0, stream>>>(deg, part, btot, n);
    scan2_kernel<<<1, 256, 0, stream>>>(btot, boff, nb1024);
    scan3_kernel<<<nb_n1, 256, 0, stream>>>(part, boff, row_ptr, cursor, n, e);
    place_mp_kernel<<<2048, 256, 0, stream>>>(src, dst, cursor, csr_src, e, n, (n + 7) / 8);

    const int gBlocks = (n + 127) / 128;
    const int nb_g = (n + 3) / 4;

    // layer 1
    mfma_gemm_kernel<128, 2, 2, false, true><<<gBlocks, 256, 0, stream>>>(X, whi1, wlo1, nullptr, bufAh, n, IN_DIM);
    gather_kernel<<<nb_g, 256, 0, stream>>>(bufAh, row_ptr, csr_src, dinv, b1, bufB, n);

    // layer 2
    mfma_gemm_kernel<128, 2, 2, false, true><<<gBlocks, 256, 0, stream>>>(bufB, whi2, wlo2, nullptr, bufAh, n, HDIM);
    gather_kernel<<<nb_g, 256, 0, stream>>>(bufAh, row_ptr, csr_src, dinv, b2, bufB, n);

    // classifier: out = h2 @ Wc + bc  (MFMA, fp32 out)
    mfma_gemm_kernel<32, 2, 2, true, false><<<gBlocks, 256, 0, stream>>>(bufB, whic, wloc, bc, out, n, HDIM);
}

// Round 6
// 340.385 us; speedup vs baseline: 5.1568x; 1.1837x over previous
//
#include <hip/hip_runtime.h>
#include <hip/hip_bf16.h>
#include <hip/hip_fp16.h>

#define IN_DIM 256
#define HDIM 128
#define CDIM 32

typedef __attribute__((ext_vector_type(8))) unsigned short u16x8;
typedef __attribute__((ext_vector_type(8))) _Float16 f16x8;
typedef __attribute__((ext_vector_type(4))) float f32x4;

__device__ __forceinline__ int swz4(int r) { return (r & 3) ^ ((r >> 2) & 3); }

// ---------------- CSR build ----------------

__global__ void zero_kernel(int* __restrict__ p, int n) {
    int i = blockIdx.x * blockDim.x + threadIdx.x;
    if (i < n) p[i] = 0;
}

__global__ void degi_kernel(const int* __restrict__ dst, int* __restrict__ deg, int e) {
    int i = blockIdx.x * blockDim.x + threadIdx.x;
    if (i < e) atomicAdd(&deg[dst[i]], 1);
}

__global__ void dinv_kernel(const int* __restrict__ deg, float* __restrict__ dinv, int n) {
    int i = blockIdx.x * blockDim.x + threadIdx.x;
    if (i < n) dinv[i] = rsqrtf((float)(deg[i] + 1));  // +1 self-loop
}

__global__ __launch_bounds__(256) void scan1_kernel(const int* __restrict__ deg,
                                                    int* __restrict__ part,
                                                    int* __restrict__ btot, int n) {
    __shared__ int sd[256];
    int t = threadIdx.x;
    int base = blockIdx.x * 1024 + t * 4;
    int v[4], sum = 0;
#pragma unroll
    for (int j = 0; j < 4; ++j) { int idx = base + j; v[j] = (idx < n) ? deg[idx] : 0; sum += v[j]; }
    sd[t] = sum;
    __syncthreads();
    for (int off = 1; off < 256; off <<= 1) {
        int x = (t >= off) ? sd[t - off] : 0;
        __syncthreads();
        sd[t] += x;
        __syncthreads();
    }
    int excl = sd[t] - sum;
#pragma unroll
    for (int j = 0; j < 4; ++j) { int idx = base + j; if (idx < n) part[idx] = excl; excl += v[j]; }
    if (t == 255) btot[blockIdx.x] = sd[255];
}

__global__ __launch_bounds__(256) void scan2_kernel(const int* __restrict__ btot,
                                                    int* __restrict__ boff, int nb) {
    __shared__ int sd[256];
    int t = threadIdx.x;
    int v = (t < nb) ? btot[t] : 0;
    sd[t] = v;
    __syncthreads();
    for (int off = 1; off < 256; off <<= 1) {
        int x = (t >= off) ? sd[t - off] : 0;
        __syncthreads();
        sd[t] += x;
        __syncthreads();
    }
    if (t < nb) boff[t] = sd[t] - v;
}

__global__ void scan3_kernel(const int* __restrict__ part, const int* __restrict__ boff,
                             int* __restrict__ row_ptr, int* __restrict__ cursor,
                             int n, int e) {
    int i = blockIdx.x * blockDim.x + threadIdx.x;
    if (i < n) {
        int v = part[i] + boff[i >> 10];
        row_ptr[i] = v;
        cursor[i] = v;
    } else if (i == n) {
        row_ptr[n] = e;
    }
}

// XCD-partitioned placement: group g = blockIdx&7 owns dst range g.
// Ranges are disjoint -> correct under any block->XCD mapping; with the
// usual round-robin mapping each csr range is written by one XCD's L2,
// eliminating partial-line writeback amplification.
__global__ __launch_bounds__(256) void place_xcd_kernel(
        const int* __restrict__ src, const int* __restrict__ dst,
        int* __restrict__ cursor, int* __restrict__ csr_src, int e, int n) {
    const int grp = blockIdx.x & 7;
    const int rs = (n + 7) >> 3;
    const int lo = grp * rs;
    const int hi = (lo + rs < n) ? lo + rs : n;
    const int nb = gridDim.x >> 3;
    const int bi = blockIdx.x >> 3;
    const int stride = nb * 256;
    for (int i = bi * 256 + threadIdx.x; i < e; i += stride) {
        int d = dst[i];
        if (d >= lo && d < hi) {
            int pos = atomicAdd(&cursor[d], 1);
            csr_src[pos] = src[i];
        }
    }
}

// ---------------- weight convert+transpose: W[K][N] fp32 -> Wt[N][K] fp16 ----------------

__global__ void wconv_kernel(const float* __restrict__ W, unsigned short* __restrict__ Wt,
                             int K, int N) {
    int i = blockIdx.x * blockDim.x + threadIdx.x;
    if (i < K * N) {
        int k = i / N, n2 = i % N;
        Wt[n2 * K + k] = __half_as_ushort(__float2half_rn(W[i]));
    }
}

// ---------------- fp16 MFMA GEMM: C = A(MxK) @ Wt^T, 128xBN tile, BK=32, dbuf LDS ----------------
// A fp32 (converted in staging) or fp16. Wt is [BN_total][K] fp16 (pre-transposed).

template<int BN, bool AF16, bool BIAS, bool OUTH>
__global__ __launch_bounds__(256) void gemm_f16_kernel(
        const void* __restrict__ Ap, const unsigned short* __restrict__ Wt,
        const float* __restrict__ bias, void* __restrict__ C, int M, int K) {
    constexpr int FM = 4;             // 128 / 2 waves / 16
    constexpr int FN = BN / 2 / 16;   // 4 (BN=128) or 1 (BN=32)
    constexpr int BU = (BN * 4 + 255) / 256;
    __shared__ __align__(16) unsigned short As[2][128 * 32];
    __shared__ __align__(16) unsigned short Bs[2][BN * 32];

    const int t = threadIdx.x;
    const int rowBase = blockIdx.x * 128;
    const int l = t & 63, w = t >> 6;
    const int wr = w >> 1, wc = w & 1;
    const int lrow = l & 15, g = l >> 4;
    const int NK = K >> 5;

    f32x4 acc[FM][FN];
#pragma unroll
    for (int i = 0; i < FM; ++i)
#pragma unroll
        for (int j = 0; j < FN; ++j) acc[i][j] = f32x4{0.f, 0.f, 0.f, 0.f};

    u16x8 aS[2];
    float4 af[2][2];
    u16x8 bS[BU];

    auto LOADA = [&](int k0) {
#pragma unroll
        for (int i = 0; i < 2; ++i) {
            int u = t + 256 * i;            // one 16B chunk: row u>>2, chunk u&3
            int r = u >> 2, c = u & 3;
            int gr = rowBase + r; if (gr > M - 1) gr = M - 1;
            if (AF16) {
                aS[i] = ((const u16x8*)((const unsigned short*)Ap + (size_t)gr * K + k0))[c];
            } else {
                const float4* ar = (const float4*)((const float*)Ap + (size_t)gr * K + k0);
                af[i][0] = ar[c * 2];
                af[i][1] = ar[c * 2 + 1];
            }
        }
    };
    auto WRITEA = [&](int buf) {
#pragma unroll
        for (int i = 0; i < 2; ++i) {
            int u = t + 256 * i;
            int r = u >> 2, c = u & 3;
            int d = r * 4 + (c ^ swz4(r));
            if (AF16) {
                ((u16x8*)As[buf])[d] = aS[i];
            } else {
                f16x8 h;
                h[0] = (_Float16)af[i][0].x; h[1] = (_Float16)af[i][0].y;
                h[2] = (_Float16)af[i][0].z; h[3] = (_Float16)af[i][0].w;
                h[4] = (_Float16)af[i][1].x; h[5] = (_Float16)af[i][1].y;
                h[6] = (_Float16)af[i][1].z; h[7] = (_Float16)af[i][1].w;
                ((f16x8*)As[buf])[d] = h;
            }
        }
    };
    auto LOADB = [&](int k0) {
#pragma unroll
        for (int i = 0; i < BU; ++i) {
            int u = t + 256 * i;
            if (u < BN * 4) {
                int nn = u >> 2, c = u & 3;
                bS[i] = ((const u16x8*)(Wt + (size_t)nn * K + k0))[c];
            }
        }
    };
    auto WRITEB = [&](int buf) {
#pragma unroll
        for (int i = 0; i < BU; ++i) {
            int u = t + 256 * i;
            if (u < BN * 4) {
                int nn = u >> 2, c = u & 3;
                ((u16x8*)Bs[buf])[nn * 4 + (c ^ swz4(nn))] = bS[i];
            }
        }
    };

    LOADA(0); LOADB(0);
    WRITEA(0); WRITEB(0);
    __syncthreads();

    for (int k = 0; k < NK; ++k) {
        int cur = k & 1;
        bool more = (k + 1 < NK);
        if (more) { LOADA((k + 1) << 5); LOADB((k + 1) << 5); }  // issue early

        f16x8 a[FM], b[FN];
#pragma unroll
        for (int fm = 0; fm < FM; ++fm) {
            int r = wr * 64 + fm * 16 + lrow;
            a[fm] = ((const f16x8*)As[cur])[r * 4 + (g ^ swz4(r))];
        }
#pragma unroll
        for (int fn = 0; fn < FN; ++fn) {
            int nn = wc * (FN * 16) + fn * 16 + lrow;
            b[fn] = ((const f16x8*)Bs[cur])[nn * 4 + (g ^ swz4(nn))];
        }
#pragma unroll
        for (int fm = 0; fm < FM; ++fm)
#pragma unroll
            for (int fn = 0; fn < FN; ++fn)
                acc[fm][fn] = __builtin_amdgcn_mfma_f32_16x16x32_f16(a[fm], b[fn], acc[fm][fn], 0, 0, 0);

        if (more) { WRITEA(cur ^ 1); WRITEB(cur ^ 1); }          // write late (after MFMA)
        __syncthreads();
    }

    // C/D layout: col = lane&15, row = (lane>>4)*4 + reg
#pragma unroll
    for (int fm = 0; fm < FM; ++fm)
#pragma unroll
        for (int fn = 0; fn < FN; ++fn) {
            int col = wc * (FN * 16) + fn * 16 + lrow;
#pragma unroll
            for (int r = 0; r < 4; ++r) {
                int row = rowBase + wr * 64 + fm * 16 + g * 4 + r;
                if (row < M) {
                    float v = acc[fm][fn][r];
                    if (BIAS) v += bias[col];
                    if (OUTH) ((__half*)C)[(size_t)row * BN + col] = __float2half_rn(v);
                    else      ((float*)C)[(size_t)row * BN + col] = v;
                }
            }
        }
}

// ---------------- gather aggregation (fp16 in, fp16 out; fused self-loop + bias + relu) ----------------
// out[d,:] = relu( dinv[d] * ( sum_{s in N(d)} dinv[s]*x[s,:] + dinv[d]*x[d,:] ) + bias )

__global__ __launch_bounds__(256) void gather_kernel(
        const __half* __restrict__ x, const int* __restrict__ row_ptr,
        const int* __restrict__ csr_src, const float* __restrict__ dinv,
        const float* __restrict__ bias, __half* __restrict__ out, int n) {
    int node = __builtin_amdgcn_readfirstlane(blockIdx.x * 4 + (threadIdx.x >> 6));
    if (node >= n) return;
    int lane = threadIdx.x & 63;
    const __half2* xv = (const __half2*)x;   // row = 64 half2
    float dd = dinv[node];
    float2 self = __half22float2(xv[(size_t)node * 64 + lane]);
    float accx = dd * self.x, accy = dd * self.y;
    int p = row_ptr[node], end = row_ptr[node + 1];
    for (; p + 3 < end; p += 4) {
        int s0 = csr_src[p], s1 = csr_src[p + 1], s2 = csr_src[p + 2], s3 = csr_src[p + 3];
        float w0 = dinv[s0], w1 = dinv[s1], w2 = dinv[s2], w3 = dinv[s3];
        float2 v0 = __half22float2(xv[(size_t)s0 * 64 + lane]);
        float2 v1 = __half22float2(xv[(size_t)s1 * 64 + lane]);
        float2 v2 = __half22float2(xv[(size_t)s2 * 64 + lane]);
        float2 v3 = __half22float2(xv[(size_t)s3 * 64 + lane]);
        accx += w0 * v0.x + w1 * v1.x + w2 * v2.x + w3 * v3.x;
        accy += w0 * v0.y + w1 * v1.y + w2 * v2.y + w3 * v3.y;
    }
    for (; p < end; ++p) {
        int s0 = csr_src[p];
        float w0 = dinv[s0];
        float2 v0 = __half22float2(xv[(size_t)s0 * 64 + lane]);
        accx += w0 * v0.x;
        accy += w0 * v0.y;
    }
    float2 bb = ((const float2*)bias)[lane];
    float2 r;
    r.x = fmaxf(accx * dd + bb.x, 0.f);
    r.y = fmaxf(accy * dd + bb.y, 0.f);
    ((__half2*)out)[(size_t)node * 64 + lane] = __float22half2_rn(r);
}

// ---------------- launch ----------------

extern "C" void kernel_launch(void* const* d_in, const int* in_sizes, int n_in,
                              void* d_out, int out_size, void* d_ws, size_t ws_size,
                              hipStream_t stream) {
    const float* X  = (const float*)d_in[0];
    const int*   ei = (const int*)d_in[1];
    const float* W1 = (const float*)d_in[2];
    const float* b1 = (const float*)d_in[3];
    const float* W2 = (const float*)d_in[4];
    const float* b2 = (const float*)d_in[5];
    const float* Wc = (const float*)d_in[6];
    const float* bc = (const float*)d_in[7];
    float* out = (float*)d_out;

    const int n = in_sizes[0] / IN_DIM;   // 100000
    const int e = in_sizes[1] / 2;        // 1600000
    const int* src = ei;
    const int* dst = ei + e;

    // workspace layout
    char* ws = (char*)d_ws;
    auto align = [](size_t x) { return (x + 255) & ~(size_t)255; };
    size_t off = 0;
    float* dinv   = (float*)(ws + off); off += align((size_t)n * 4);
    int* deg      = (int*)(ws + off);   off += align((size_t)n * 4);
    int* part     = (int*)(ws + off);   off += align((size_t)n * 4);
    int* cursor   = (int*)(ws + off);   off += align((size_t)n * 4);
    int* row_ptr  = (int*)(ws + off);   off += align((size_t)(n + 1) * 4);
    int* btot     = (int*)(ws + off);   off += align(256 * 4);
    int* boff     = (int*)(ws + off);   off += align(256 * 4);
    int* csr_src  = (int*)(ws + off);   off += align((size_t)e * 4);
    unsigned short* w1t = (unsigned short*)(ws + off); off += align((size_t)IN_DIM * HDIM * 2);
    unsigned short* w2t = (unsigned short*)(ws + off); off += align((size_t)HDIM * HDIM * 2);
    unsigned short* wct = (unsigned short*)(ws + off); off += align((size_t)HDIM * CDIM * 2);
    __half* bufAh = (__half*)(ws + off); off += align((size_t)n * HDIM * 2);
    __half* bufBh = (__half*)(ws + off); off += align((size_t)n * HDIM * 2);

    const int nb_n  = (n + 255) / 256;
    const int nb_n1 = (n + 256) / 256;
    const int nb_e  = (e + 255) / 256;
    const int nb1024 = (n + 1023) / 1024;

    // ---- weight convert+transpose (fp16) ----
    wconv_kernel<<<(IN_DIM * HDIM + 255) / 256, 256, 0, stream>>>(W1, w1t, IN_DIM, HDIM);
    wconv_kernel<<<(HDIM * HDIM + 255) / 256, 256, 0, stream>>>(W2, w2t, HDIM, HDIM);
    wconv_kernel<<<(HDIM * CDIM + 255) / 256, 256, 0, stream>>>(Wc, wct, HDIM, CDIM);

    // ---- CSR build (shared by both layers) ----
    zero_kernel<<<nb_n, 256, 0, stream>>>(deg, n);
    degi_kernel<<<nb_e, 256, 0, stream>>>(dst, deg, e);
    dinv_kernel<<<nb_n, 256, 0, stream>>>(deg, dinv, n);
    scan1_kernel<<<nb1024, 256, 0, stream>>>(deg, part, btot, n);
    scan2_kernel<<<1, 256, 0, stream>>>(btot, boff, nb1024);
    scan3_kernel<<<nb_n1, 256, 0, stream>>>(part, boff, row_ptr, cursor, n, e);
    place_xcd_kernel<<<2048, 256, 0, stream>>>(src, dst, cursor, csr_src, e, n);

    const int gBlocks = (n + 127) / 128;
    const int nb_g = (n + 3) / 4;

    // layer 1: fp32 X -> fp16 h
    gemm_f16_kernel<128, false, false, true><<<gBlocks, 256, 0, stream>>>(X, w1t, nullptr, bufAh, n, IN_DIM);
    gather_kernel<<<nb_g, 256, 0, stream>>>(bufAh, row_ptr, csr_src, dinv, b1, bufBh, n);

    // layer 2: fp16 -> fp16
    gemm_f16_kernel<128, true, false, true><<<gBlocks, 256, 0, stream>>>(bufBh, w2t, nullptr, bufAh, n, HDIM);
    gather_kernel<<<nb_g, 256, 0, stream>>>(bufAh, row_ptr, csr_src, dinv, b2, bufBh, n);

    // classifier: fp16 -> fp32 out, fused bias
    gemm_f16_kernel<32, true, true, false><<<gBlocks, 256, 0, stream>>>(bufBh, wct, bc, out, n, HDIM);
}